// Round 2
// baseline (936.119 us; speedup 1.0000x reference)
//
#include <hip/hip_runtime.h>
#include <hip/hip_bf16.h>

typedef __hip_bfloat16 bf16;
typedef __attribute__((ext_vector_type(8))) short short8;   // 8 x bf16 (4 VGPRs)
typedef __attribute__((ext_vector_type(4))) float f32x4;

#define Hdim 512
#define Bdim 512
#define Tdim 64
#define Fdim 64
#define NC   4

__device__ __forceinline__ float sigmoidf_(float x){ return 1.f/(1.f + __expf(-x)); }
__device__ __forceinline__ float tanhf_(float x){
  float t = __expf(-2.f*fabsf(x));
  float r = (1.f - t)/(1.f + t);
  return copysignf(r, x);
}
__device__ __forceinline__ float bf2f_(short u){
  return __uint_as_float(((unsigned)(unsigned short)u) << 16);
}
__device__ __forceinline__ short f2bf_(float f){
  bf16 b = (bf16)f;
  return *(short*)&b;
}

// ---------------- fp32 -> bf16 pack (fc_in_W only) ----------------
__global__ __launch_bounds__(256) void pack_kernel(const float* __restrict__ src,
                                                   bf16* __restrict__ dst, int n){
  int idx = (blockIdx.x*256 + threadIdx.x)*4;
  if (idx < n){
    float4 v = *(const float4*)(src + idx);
    dst[idx+0] = (bf16)v.x;
    dst[idx+1] = (bf16)v.y;
    dst[idx+2] = (bf16)v.z;
    dst[idx+3] = (bf16)v.w;
  }
}

// ---------------- transpose data [B][F][T] fp32 -> dataT [T][B][F] bf16 ----------------
__global__ __launch_bounds__(256) void transpose_kernel(const float* __restrict__ data,
                                                        bf16* __restrict__ dataT){
  __shared__ bf16 tile[64*65];
  int b = blockIdx.x;
  int tid = threadIdx.x;
  for (int i = 0; i < 16; ++i){
    int idx = tid + i*256;
    int f = idx >> 6, t = idx & 63;
    tile[f*65 + t] = (bf16)data[(b*64 + f)*64 + t];
  }
  __syncthreads();
  for (int i = 0; i < 16; ++i){
    int idx = tid + i*256;
    int t = idx >> 6, f = idx & 63;
    dataT[(t*Bdim + b)*64 + f] = tile[f*65 + t];
  }
}

// ---------------- init: h(-1) bf16 shadow, owner-major 16-col chunks ----------------
// layout: [ (k*2+bt)*32 + chunk ][ b_local(256) ][ 16 ]
__global__ __launch_bounds__(256) void init_kernel(const float* __restrict__ init_h,
                            bf16* __restrict__ h_b1, unsigned* __restrict__ flags){
  int idx = blockIdx.x*256 + threadIdx.x;          // 0 .. 4*512*512-1
  int k = idx >> 18;
  int rem = idx & 262143;                          // b_glob*512 + o
  int bg = rem >> 9;
  int o  = rem & 511;
  int dst = ((k*2 + (bg >> 8))*32 + (o >> 4))*4096 + (bg & 255)*16 + (o & 15);
  h_b1[dst] = (bf16)init_h[rem];
  if (idx < 512) flags[idx] = 0u;                  // flags[8][32] + xslot[8][32]
}

// ---------------- input projection: x_seq[s][k][b][h] = relu(dataT[src_t] @ fc_in_W[k]^T + b)
__global__ __launch_bounds__(256) void proj_kernel(const bf16* __restrict__ dataT,
    const bf16* __restrict__ fc_in_W, const float* __restrict__ fc_in_b,
    bf16* __restrict__ x_seq){
  __shared__ short ldsA[64*72];
  __shared__ short ldsW[128*72];
  int blk = blockIdx.x;
  int s  = blk >> 7;
  int k  = (blk >> 5) & 3;
  int bt = (blk >> 2) & 7;
  int on = blk & 3;
  int tid = threadIdx.x;
  int lane = tid & 63, wid = tid >> 6;
  int quad = lane >> 4, l16 = lane & 15;
  int src_t = (k < 2) ? s : (Tdim - 1 - s);

  const short* Ag = (const short*)(dataT + (src_t*Bdim + bt*64)*Fdim);
  #pragma unroll
  for (int i = 0; i < 2; ++i){
    int c = tid + i*256; int r = c >> 3, off = c & 7;
    *(int4*)(&ldsA[r*72 + off*8]) = *(const int4*)(&Ag[r*64 + off*8]);
  }
  const short* Wg = (const short*)(fc_in_W + (k*Hdim + on*128)*Fdim);
  #pragma unroll
  for (int i = 0; i < 4; ++i){
    int c = tid + i*256; int r = c >> 3, off = c & 7;
    *(int4*)(&ldsW[r*72 + off*8]) = *(const int4*)(&Wg[r*64 + off*8]);
  }
  __syncthreads();

  f32x4 acc[2][4];
  #pragma unroll
  for (int nt=0; nt<2; ++nt)
    #pragma unroll
    for (int rb=0; rb<4; ++rb) acc[nt][rb] = (f32x4){0.f,0.f,0.f,0.f};

  #pragma unroll
  for (int kk = 0; kk < 2; ++kk){
    int io = kk*32 + quad*8;
    short8 a[4];
    #pragma unroll
    for (int rb=0; rb<4; ++rb) a[rb] = *(const short8*)(&ldsA[(rb*16+l16)*72 + io]);
    #pragma unroll
    for (int nt=0; nt<2; ++nt){
      short8 bw = *(const short8*)(&ldsW[(wid*32 + nt*16 + l16)*72 + io]);
      #pragma unroll
      for (int rb=0; rb<4; ++rb)
        acc[nt][rb] = __builtin_amdgcn_mfma_f32_16x16x32_bf16(a[rb], bw, acc[nt][rb], 0,0,0);
    }
  }

  #pragma unroll
  for (int nt=0; nt<2; ++nt){
    int o = on*128 + wid*32 + nt*16 + l16;
    float bias = fc_in_b[k*Hdim + o];
    #pragma unroll
    for (int rb=0; rb<4; ++rb){
      #pragma unroll
      for (int reg=0; reg<4; ++reg){
        int b = bt*64 + rb*16 + quad*4 + reg;
        float v = acc[nt][rb][reg] + bias;
        v = v > 0.f ? v : 0.f;
        x_seq[((size_t)(s*NC + k)*Bdim + b)*Hdim + o] = (bf16)v;
      }
    }
  }
}

// ---------------- persistent GRU, FUSED per-CU producer+consumer (r15) ---------
// r15 vs r13/r14: producer/consumer split removed. All 32 CUs of an XCD own a
// 16-col o-tile each (j=0..31) and do BOTH GEMMs (x@Wih^T and h@Whh^T, same
// total FLOP/CU as the split). Key properties:
//  (1) gi lives in f32 REGISTERS (depth-2 static ring giA/giB, 2x-unrolled
//      loop): the 6.3 MB/step gi L2 round-trip, bf16 pack/unpack, and the
//      entire producer flag domain are gone.
//  (2) x-GEMM for step s+1 is issued BEFORE the step-s flag wait. It has no
//      h dependence, so ~2.5us of independent work covers inter-CU skew and
//      flag L2 visibility: the rendezvous is reached already-satisfied.
//  (3) r13's proven sync shape is kept: single wave (wid 0) polls all 32
//      h-flags, __syncthreads broadcast; epilogue stores -> __syncthreads
//      (vmcnt drain) -> flag bump -> off-path part dot. No per-wave polling
//      (r14 lesson: 8x flag traffic + in-GEMM branches cost 11%).
// WAR invariant unchanged: flags >= s observed before h-GEMM(s) implies every
// CU finished reading h(s-2), so writing h_out(s) (same buffer) is safe.
__global__ __launch_bounds__(512, 2) void rnn_kernel(
    const bf16* __restrict__ x_seq, const float* __restrict__ init_h,
    bf16* __restrict__ h_b0, bf16* __restrict__ h_b1,
    const float* __restrict__ Wih, const float* __restrict__ Whh,
    const float* __restrict__ bih, const float* __restrict__ bhh,
    const float* __restrict__ fc_out_W,
    float* __restrict__ part,
    unsigned* __restrict__ flags, unsigned* __restrict__ xslot)
{
  __shared__ short wlds[2*3*16*512];   // 96 KB: [side2][gate3][kc16][lane64] x 8 bf16
  __shared__ int sslot;

  int tid = threadIdx.x;
  int lane = tid & 63, wid = tid >> 6;          // wid 0..7
  int quad = lane >> 4, l16 = lane & 15;

  // ---- physical-XCD self-assignment (1 block/CU pigeonhole: 256 blocks) ----
  unsigned xcc;
  asm volatile("s_getreg_b32 %0, hwreg(HW_REG_XCC_ID)" : "=s"(xcc));
  xcc &= 7u;
  if (tid == 0)
    sslot = (int)__hip_atomic_fetch_add(&xslot[xcc*32], 1u,
                __ATOMIC_RELAXED, __HIP_MEMORY_SCOPE_WORKGROUP);
  __syncthreads();
  int grp = (int)xcc;
  int k   = grp >> 1;
  int bt  = grp & 1;
  int j   = sslot & 31;                // o-tile 0..31 (16 cols each)
  int rot = j & 15;                    // K-ring phase stagger
  unsigned* gflags = flags + grp*32;   // 32 h-flags for this group

  // ---- both weight sides -> LDS once, fp32->bf16, B-fragment lane order ----
  // linear item i = (side*3+gate)*1024 + kc*64 + ln ; 8 bf16 per item
  for (int i = tid; i < 6144; i += 512){
    int side = (i >= 3072);
    int i2   = i - side*3072;
    int plane = i2 >> 10;
    int rem2  = i2 & 1023;
    int kc    = rem2 >> 6;
    int ln    = rem2 & 63;
    int ll16  = ln & 15, lq = ln >> 4;
    const float* Wsrc = side ? Whh : Wih;
    const float* srcp = Wsrc +
        ((size_t)(k*3 + plane)*Hdim + j*16 + ll16)*Hdim + kc*32 + lq*8;
    float4 f0 = *(const float4*)srcp;
    float4 f1 = *(const float4*)(srcp + 4);
    short8 pk;
    pk[0]=f2bf_(f0.x); pk[1]=f2bf_(f0.y); pk[2]=f2bf_(f0.z); pk[3]=f2bf_(f0.w);
    pk[4]=f2bf_(f1.x); pk[5]=f2bf_(f1.y); pk[6]=f2bf_(f1.z); pk[7]=f2bf_(f1.w);
    *(int4*)(&wlds[i*8]) = *(int4*)&pk;
  }

  // ---- per-thread constants: biases, output weight, fp32 h state ----
  int o0 = j*16 + l16;
  float br  = bih[k*3*Hdim + o0] + bhh[k*3*Hdim + o0];
  float bz  = bih[k*3*Hdim + Hdim + o0] + bhh[k*3*Hdim + Hdim + o0];
  float bnx = bih[k*3*Hdim + 2*Hdim + o0];
  float bnh = bhh[k*3*Hdim + 2*Hdim + o0];
  float wout = fc_out_W[(k & 1)*Hdim + o0];

  float hk[2][4];   // [rb][reg]
  #pragma unroll
  for (int rb=0; rb<2; ++rb)
    #pragma unroll
    for (int reg=0; reg<4; ++reg)
      hk[rb][reg] =
        init_h[(bt*256 + wid*32 + rb*16 + quad*4 + reg)*Hdim + o0];

  const size_t hgbase = (size_t)((k*2 + bt)*32) * 4096;  // group h base (shorts)

  __syncthreads();   // LDS fill complete

  // x-GEMM: A rows stride Hdim, K-chunk c at col offset c*32. Wih = side 0.
  #define GEMM16X(ABASE, ACC) do {                                              \
    _Pragma("unroll")                                                           \
    for (int g=0; g<3; ++g){ ACC[g][0] = (f32x4){0.f,0.f,0.f,0.f};              \
                             ACC[g][1] = (f32x4){0.f,0.f,0.f,0.f}; }            \
    const short* ap0_ = (ABASE) + (wid*32 + l16)*Hdim + quad*8;                 \
    const short* ap1_ = ap0_ + 16*Hdim;                                         \
    short8 ab_[4][2];                                                           \
    _Pragma("unroll")                                                           \
    for (int d=0; d<4; ++d){                                                    \
      int c_ = (d + rot) & 15;                                                  \
      ab_[d][0] = *(const short8*)(ap0_ + c_*32);                               \
      ab_[d][1] = *(const short8*)(ap1_ + c_*32);                               \
    }                                                                           \
    short8 bb_[2][3];                                                           \
    _Pragma("unroll")                                                           \
    for (int g=0; g<3; ++g)                                                     \
      bb_[0][g] = *(const short8*)(&wlds[((g*16 + rot)<<9) + (lane<<3)]);       \
    _Pragma("unroll")                                                           \
    for (int kc=0; kc<16; ++kc){                                                \
      short8 a0_ = ab_[kc&3][0], a1_ = ab_[kc&3][1];                            \
      if (kc < 12){                                                             \
        int c_ = (kc + 4 + rot) & 15;                                           \
        ab_[kc&3][0] = *(const short8*)(ap0_ + c_*32);                          \
        ab_[kc&3][1] = *(const short8*)(ap1_ + c_*32);                          \
      }                                                                         \
      if (kc < 15){                                                             \
        int c_ = (kc + 1 + rot) & 15;                                           \
        _Pragma("unroll")                                                       \
        for (int g=0; g<3; ++g)                                                 \
          bb_[(kc+1)&1][g] = *(const short8*)(&wlds[((g*16 + c_)<<9) + (lane<<3)]); \
      }                                                                         \
      _Pragma("unroll")                                                         \
      for (int g=0; g<3; ++g){                                                  \
        short8 bw_ = bb_[kc&1][g];                                              \
        ACC[g][0] = __builtin_amdgcn_mfma_f32_16x16x32_bf16(a0_, bw_, ACC[g][0], 0,0,0); \
        ACC[g][1] = __builtin_amdgcn_mfma_f32_16x16x32_bf16(a1_, bw_, ACC[g][1], 0,0,0); \
      }                                                                         \
    }                                                                           \
  } while(0)

  // h-GEMM: owner-major 16-col chunks, chunk (2kc + quad>>1) at offset kc*8192.
  // Whh = side 1 (LDS offset (3+g)).
  #define GEMM16H(HCB, ACC) do {                                                \
    _Pragma("unroll")                                                           \
    for (int g=0; g<3; ++g){ ACC[g][0] = (f32x4){0.f,0.f,0.f,0.f};              \
                             ACC[g][1] = (f32x4){0.f,0.f,0.f,0.f}; }            \
    const short* hp0_ = (HCB) + (quad>>1)*4096 + (wid*32 + l16)*16 + (quad&1)*8;\
    const short* hp1_ = hp0_ + 256;                                             \
    short8 ab_[4][2];                                                           \
    _Pragma("unroll")                                                           \
    for (int d=0; d<4; ++d){                                                    \
      int c_ = (d + rot) & 15;                                                  \
      ab_[d][0] = *(const short8*)(hp0_ + c_*8192);                             \
      ab_[d][1] = *(const short8*)(hp1_ + c_*8192);                             \
    }                                                                           \
    short8 bb_[2][3];                                                           \
    _Pragma("unroll")                                                           \
    for (int g=0; g<3; ++g)                                                     \
      bb_[0][g] = *(const short8*)(&wlds[(((3+g)*16 + rot)<<9) + (lane<<3)]);   \
    _Pragma("unroll")                                                           \
    for (int kc=0; kc<16; ++kc){                                                \
      short8 a0_ = ab_[kc&3][0], a1_ = ab_[kc&3][1];                            \
      if (kc < 12){                                                             \
        int c_ = (kc + 4 + rot) & 15;                                           \
        ab_[kc&3][0] = *(const short8*)(hp0_ + c_*8192);                        \
        ab_[kc&3][1] = *(const short8*)(hp1_ + c_*8192);                        \
      }                                                                         \
      if (kc < 15){                                                             \
        int c_ = (kc + 1 + rot) & 15;                                           \
        _Pragma("unroll")                                                       \
        for (int g=0; g<3; ++g)                                                 \
          bb_[(kc+1)&1][g] = *(const short8*)(&wlds[(((3+g)*16 + c_)<<9) + (lane<<3)]); \
      }                                                                         \
      _Pragma("unroll")                                                         \
      for (int g=0; g<3; ++g){                                                  \
        short8 bw_ = bb_[kc&1][g];                                              \
        ACC[g][0] = __builtin_amdgcn_mfma_f32_16x16x32_bf16(a0_, bw_, ACC[g][0], 0,0,0); \
        ACC[g][1] = __builtin_amdgcn_mfma_f32_16x16x32_bf16(a1_, bw_, ACC[g][1], 0,0,0); \
      }                                                                         \
    }                                                                           \
  } while(0)

  // one full timestep; GCUR = gi(S) (consumed), GNXT = gi(S+1) (produced)
  #define STEP(S, GCUR, GNXT) do {                                              \
    if ((S) < 63){                                                              \
      const short* xb_ = (const short*)(x_seq +                                 \
          ((size_t)(((S)+1)*NC + k)*Bdim + bt*256)*Hdim);                       \
      GEMM16X(xb_, GNXT);                                                       \
    }                                                                           \
    if ((S) > 0){                                                               \
      if (wid == 0){                                                            \
        int g_ = 0;                                                             \
        for (;;){                                                               \
          unsigned v_ = 0xFFFFFFFFu;                                            \
          if (lane < 32)                                                        \
            v_ = __hip_atomic_load(&gflags[lane], __ATOMIC_RELAXED,             \
                                   __HIP_MEMORY_SCOPE_AGENT);                   \
          if (__ballot(v_ >= (unsigned)(S)) == ~0ull) break;                    \
          __builtin_amdgcn_s_sleep(1);                                          \
          if (++g_ > 4000000) break;                                            \
        }                                                                       \
      }                                                                         \
      __syncthreads();                                                          \
    }                                                                           \
    const bf16* h_in_  = ((S) & 1) ? h_b0 : h_b1;                               \
    bf16*       h_out_ = ((S) & 1) ? h_b1 : h_b0;                               \
    f32x4 hacc_[3][2];                                                          \
    GEMM16H((const short*)h_in_ + hgbase, hacc_);                               \
    bf16* hob_ = h_out_ + hgbase + (size_t)j*4096;                              \
    _Pragma("unroll")                                                           \
    for (int rb = 0; rb < 2; ++rb){                                             \
      _Pragma("unroll")                                                         \
      for (int reg = 0; reg < 4; ++reg){                                        \
        int bl_ = wid*32 + rb*16 + quad*4 + reg;                                \
        float r_ = sigmoidf_(GCUR[0][rb][reg] + hacc_[0][rb][reg] + br);        \
        float z_ = sigmoidf_(GCUR[1][rb][reg] + hacc_[1][rb][reg] + bz);        \
        float n_ = tanhf_(GCUR[2][rb][reg] + bnx + r_*(hacc_[2][rb][reg] + bnh)); \
        float hn_ = (1.f - z_)*n_ + z_*hk[rb][reg];                             \
        hk[rb][reg] = hn_;                                                      \
        hob_[bl_*16 + l16] = (bf16)hn_;                                         \
      }                                                                         \
    }                                                                           \
    __syncthreads();                   /* drains vmcnt(0): h in local L2 */     \
    if (tid == 0)                                                               \
      __hip_atomic_fetch_add(&gflags[j], 1u,                                    \
                             __ATOMIC_RELAXED, __HIP_MEMORY_SCOPE_AGENT);       \
    int tmap_ = (k < 2) ? (S) : (Tdim - 1 - (S));                               \
    _Pragma("unroll")                                                           \
    for (int rb = 0; rb < 2; ++rb){                                             \
      _Pragma("unroll")                                                         \
      for (int reg = 0; reg < 4; ++reg){                                        \
        int bl_ = wid*32 + rb*16 + quad*4 + reg;                                \
        float v_ = hk[rb][reg]*wout;                                            \
        v_ += __shfl_xor(v_, 1, 64);                                            \
        v_ += __shfl_xor(v_, 2, 64);                                            \
        v_ += __shfl_xor(v_, 4, 64);                                            \
        v_ += __shfl_xor(v_, 8, 64);                                            \
        if (l16 == 0)                                                           \
          __builtin_nontemporal_store(v_,                                       \
            &part[((size_t)(k*Tdim + tmap_)*Bdim + bt*256 + bl_)*32 + j]);      \
      }                                                                         \
    }                                                                           \
  } while(0)

  // ---- prologue: gi(0); main loop 2x-unrolled for the static register ring ----
  f32x4 giA[3][2], giB[3][2];
  {
    const short* xb0 = (const short*)(x_seq + ((size_t)(k)*Bdim + bt*256)*Hdim);
    GEMM16X(xb0, giA);
  }
  for (int sp = 0; sp < 32; ++sp){
    STEP(2*sp,     giA, giB);
    STEP(2*sp + 1, giB, giA);
  }
  #undef STEP
  #undef GEMM16X
  #undef GEMM16H
}

// ---------------- out[head][b][t] = bias + sum over {head,head+2} x 32 j-partials ----
// part layout [K][T][B][32]: per-thread reads are 128 B contiguous.
__global__ __launch_bounds__(256) void finalize_kernel(const float* __restrict__ part,
                                const float* __restrict__ fc_out_b, float* __restrict__ out){
  int idx = blockIdx.x*256 + threadIdx.x;  // 0..65535
  int head = idx >> 15;
  int b = (idx >> 6) & 511;
  int t = idx & 63;
  float v = fc_out_b[head];
  #pragma unroll
  for (int kk = 0; kk < 2; ++kk){
    const float4* p = (const float4*)(part +
        ((size_t)((head + kk*2)*Tdim + t)*Bdim + b)*32);
    #pragma unroll
    for (int jj = 0; jj < 8; ++jj){
      float4 q = p[jj];
      v += q.x + q.y + q.z + q.w;
    }
  }
  out[idx] = v;
}

extern "C" void kernel_launch(void* const* d_in, const int* in_sizes, int n_in,
                              void* d_out, int out_size, void* d_ws, size_t ws_size,
                              hipStream_t stream){
  (void)in_sizes; (void)n_in; (void)out_size; (void)ws_size;
  const float* data     = (const float*)d_in[0];
  const float* init_h   = (const float*)d_in[1];
  const float* fc_in_W  = (const float*)d_in[2];
  const float* fc_in_b  = (const float*)d_in[3];
  const float* Wih      = (const float*)d_in[4];
  const float* Whh      = (const float*)d_in[5];
  const float* bih      = (const float*)d_in[6];
  const float* bhh      = (const float*)d_in[7];
  const float* fc_out_W = (const float*)d_in[8];
  const float* fc_out_b = (const float*)d_in[9];
  float* out = (float*)d_out;

  char* ws = (char*)d_ws;
  bf16*  x_seq   = (bf16*)ws;                     // [T][K][B][H] bf16 : 134217728 B
  bf16*  h_b0    = (bf16*)(ws + 134217728);       // [grp*32+c][b][16] :  2097152 B
  bf16*  h_b1    = (bf16*)(ws + 136314880);       //                      2097152 B
  float* part    = (float*)(ws + 138412032);      // [K][T][B][32] f32: 16777216 B
  bf16*  dataT   = (bf16*)(ws + 138412032);       // overlay (dead before rnn): 4 MB
  bf16*  fcW_bf  = (bf16*)(ws + 165675008);       // [K][H][F] bf16 :      262144 B
  unsigned* flags= (unsigned*)(ws + 165937152);   // [8][32] u32 = 1024 B
  unsigned* xslot= (unsigned*)(ws + 165938176);   // [8][32] u32 = 1024 B

  const int nFW = NC*Hdim*Fdim;     // 131,072
  hipLaunchKernelGGL(pack_kernel, dim3(nFW/1024), dim3(256), 0, stream, fc_in_W, fcW_bf, nFW);
  hipLaunchKernelGGL(init_kernel, dim3(4096), dim3(256), 0, stream, init_h, h_b1, flags);
  hipLaunchKernelGGL(transpose_kernel, dim3(512), dim3(256), 0, stream, data, dataT);
  hipLaunchKernelGGL(proj_kernel, dim3(8192), dim3(256), 0, stream, dataT, fcW_bf, fc_in_b, x_seq);
  hipLaunchKernelGGL(rnn_kernel, dim3(256), dim3(512), 0, stream,
      x_seq, init_h, h_b0, h_b1, Wih, Whh, bih, bhh, fc_out_W, part, flags, xslot);
  hipLaunchKernelGGL(finalize_kernel, dim3(256), dim3(256), 0, stream, part, fc_out_b, out);
}